// Round 17
// baseline (440.675 us; speedup 1.0000x reference)
//
#include <hip/hip_runtime.h>

#define DIM 128
#define NLAYERS 3
#define NGRAPHS 128
#define BN_EPS 1e-5f
#define NSTAT 64   // replicated stat copies (atomic contention fix)

typedef __attribute__((ext_vector_type(8))) short short8v;
typedef __attribute__((ext_vector_type(8))) unsigned short ushort8v;
typedef __attribute__((ext_vector_type(4))) float f32x4;

__device__ __forceinline__ unsigned short f2bf(float f) {
  unsigned int x = __float_as_uint(f);
  unsigned int r = (x + 0x7fffu + ((x >> 16) & 1u)) >> 16;  // RTNE
  return (unsigned short)r;
}
__device__ __forceinline__ float bflo(unsigned int u) { return __uint_as_float(u << 16); }
__device__ __forceinline__ float bfhi(unsigned int u) { return __uint_as_float(u & 0xffff0000u); }
__device__ __forceinline__ float bf2f(unsigned short u) {
  return __uint_as_float(((unsigned int)u) << 16);
}

// ---------------- CSR build via bucketed counting sort ----------------

#define P1CH 4096

__global__ __launch_bounds__(256) void p1_kernel(const int* __restrict__ src,
                                                 const int* __restrict__ dst,
                                                 int* __restrict__ bucketCursor,
                                                 unsigned int* __restrict__ pairs,
                                                 int stride, int E, int NB) {
  __shared__ int cnt[128];
  __shared__ int base[128];
  int t = threadIdx.x;
  int e0 = blockIdx.x * P1CH;
  int e1 = min(e0 + P1CH, E);
  if (t < NB) cnt[t] = 0;
  __syncthreads();
  for (int e = e0 + t; e < e1; e += 256) atomicAdd(&cnt[dst[e] >> 10], 1);
  __syncthreads();
  if (t < NB) {
    base[t] = atomicAdd(&bucketCursor[t], cnt[t]);
    cnt[t] = 0;
  }
  __syncthreads();
  for (int e = e0 + t; e < e1; e += 256) {
    int d = dst[e];
    int b = d >> 10;
    int p = atomicAdd(&cnt[b], 1) + base[b];
    pairs[(size_t)b * stride + p] = ((unsigned int)(d & 1023) << 20) | (unsigned int)src[e];
  }
}

__global__ __launch_bounds__(128) void bscan2_kernel(const int* __restrict__ bucketCursor,
                                                     int* __restrict__ bucketBase,
                                                     int* __restrict__ offsets, int NB, int N) {
  __shared__ int p[128];
  int t = threadIdx.x;
  p[t] = (t < NB) ? bucketCursor[t] : 0;
  __syncthreads();
  for (int off = 1; off < 128; off <<= 1) {
    int v = (t >= off) ? p[t - off] : 0;
    __syncthreads();
    p[t] += v;
    __syncthreads();
  }
  if (t < NB) bucketBase[t] = (t == 0) ? 0 : p[t - 1];
  if (t == 0) offsets[N] = p[127];
}

__global__ __launch_bounds__(1024) void p2_kernel(const unsigned int* __restrict__ pairs,
                                                  const int* __restrict__ bucketCursor,
                                                  const int* __restrict__ bucketBase,
                                                  int stride, int* __restrict__ offsets,
                                                  int* __restrict__ eidx, int N) {
  __shared__ int cur[1024];
  int b = blockIdx.x;
  int t = threadIdx.x;
  int sz = bucketCursor[b];
  int ebase = bucketBase[b];
  const unsigned int* pp = pairs + (size_t)b * stride;
  cur[t] = 0;
  __syncthreads();
  for (int i = t; i < sz; i += 1024) atomicAdd(&cur[pp[i] >> 20], 1);
  __syncthreads();
  int v = cur[t];
  __syncthreads();
  cur[t] = v;
  __syncthreads();
  for (int off = 1; off < 1024; off <<= 1) {
    int u = (t >= off) ? cur[t - off] : 0;
    __syncthreads();
    cur[t] += u;
    __syncthreads();
  }
  int excl = cur[t] - v;
  int node = b * 1024 + t;
  if (node < N) offsets[node] = ebase + excl;
  cur[t] = excl;
  __syncthreads();
  for (int i = t; i < sz; i += 1024) {
    unsigned int pv = pp[i];
    int p = atomicAdd(&cur[pv >> 20], 1);
    eidx[ebase + p] = (int)(pv & 0xFFFFFu);
  }
}

// ---------------- conversions ----------------

__global__ __launch_bounds__(256) void convx_kernel(const float* __restrict__ x,
                                                    unsigned short* __restrict__ out,
                                                    int nquads) {
  int i = blockIdx.x * 256 + threadIdx.x;
  if (i < nquads) {
    float4 v = ((const float4*)x)[i];
    ushort4 o;
    o.x = f2bf(v.x); o.y = f2bf(v.y); o.z = f2bf(v.z); o.w = f2bf(v.w);
    ((ushort4*)out)[i] = o;
  }
}

__global__ __launch_bounds__(256) void convw_kernel(const float* __restrict__ W1,
                                                    const float* __restrict__ W2,
                                                    unsigned short* __restrict__ Wt) {
  int m = blockIdx.x;
  const float* W = (m < 3) ? (W1 + (size_t)m * 16384) : (W2 + (size_t)(m - 3) * 16384);
  unsigned short* out = Wt + (size_t)m * 16384;
  __shared__ unsigned short t[128 * 130];
  for (int i = threadIdx.x; i < 16384; i += 256) {
    int k = i >> 7, n = i & 127;
    t[n * 130 + k] = f2bf(W[i]);
  }
  __syncthreads();
  for (int i = threadIdx.x; i < 16384; i += 256) {
    int n = i >> 7, k = i & 127;
    out[i] = t[n * 130 + k];
  }
}

// per-graph node counts (batch is sorted)
__global__ __launch_bounds__(128) void cnt_kernel(const int* __restrict__ batch,
                                                  int* __restrict__ cntG, int N) {
  int g = threadIdx.x;
  int lo = 0, hi = N;
  while (lo < hi) { int mid = (lo + hi) >> 1; if (batch[mid] < g) lo = mid + 1; else hi = mid; }
  int a = lo;
  lo = 0; hi = N;
  while (lo < hi) { int mid = (lo + hi) >> 1; if (batch[mid] < g + 1) lo = mid + 1; else hi = mid; }
  cntG[g] = lo - a;
}

// ---------------- BN fold: sum NSTAT replicas -> sc[128], sh[128] ----------------

__global__ __launch_bounds__(128) void bnfold_kernel(const float* __restrict__ statsRaw,
                                                     const float* __restrict__ gammaL,
                                                     const float* __restrict__ betaL,
                                                     float invN, float* __restrict__ folded) {
  int d = threadIdx.x;
  float s = 0.f, q = 0.f;
#pragma unroll
  for (int k = 0; k < NSTAT; ++k) {
    s += statsRaw[k * 256 + d];
    q += statsRaw[k * 256 + 128 + d];
  }
  float mu = s * invN;
  float var = q * invN - mu * mu;
  float sc = gammaL[d] * rsqrtf(var + BN_EPS);
  folded[d] = sc;
  folded[128 + d] = betaL[d] - mu * sc;
}

// ---------------- aggregation with fused prev-layer BN (folded sc/sh) ----------------
// one wave per node; lane owns dims {2l, 2l+1}; 8 row-loads (2KB) in flight

__global__ __launch_bounds__(256) void agg_kernel(const unsigned short* __restrict__ uin,
                                                  const int* __restrict__ offsets,
                                                  const int* __restrict__ eidx,
                                                  unsigned short* __restrict__ zout,
                                                  const float* __restrict__ foldedPrev,
                                                  int isFirst, int N) {
  int wid = (blockIdx.x * 256 + threadIdx.x) >> 6;
  int lane = threadIdx.x & 63;
  if (wid >= N) return;
  float scx = 1.f, scy = 1.f, shx = 0.f, shy = 0.f;
  if (!isFirst) {
    int d0 = lane * 2;
    float2 scv = *(const float2*)&foldedPrev[d0];
    float2 shv = *(const float2*)&foldedPrev[128 + d0];
    scx = scv.x; scy = scv.y; shx = shv.x; shy = shv.y;
  }
  const unsigned int* h32 = (const unsigned int*)uin;
  unsigned int own = h32[(size_t)wid * 64 + lane];
  float ax = bflo(own), ay = bfhi(own);
  int beg = offsets[wid], end = offsets[wid + 1];
  int e = beg;
  for (; e + 7 < end; e += 8) {
    int s0 = eidx[e], s1 = eidx[e + 1], s2 = eidx[e + 2], s3 = eidx[e + 3];
    int s4 = eidx[e + 4], s5 = eidx[e + 5], s6 = eidx[e + 6], s7 = eidx[e + 7];
    unsigned int u0 = h32[(size_t)s0 * 64 + lane];
    unsigned int u1 = h32[(size_t)s1 * 64 + lane];
    unsigned int u2 = h32[(size_t)s2 * 64 + lane];
    unsigned int u3 = h32[(size_t)s3 * 64 + lane];
    unsigned int u4 = h32[(size_t)s4 * 64 + lane];
    unsigned int u5 = h32[(size_t)s5 * 64 + lane];
    unsigned int u6 = h32[(size_t)s6 * 64 + lane];
    unsigned int u7 = h32[(size_t)s7 * 64 + lane];
    ax += bflo(u0) + bflo(u1) + bflo(u2) + bflo(u3);
    ay += bfhi(u0) + bfhi(u1) + bfhi(u2) + bfhi(u3);
    ax += bflo(u4) + bflo(u5) + bflo(u6) + bflo(u7);
    ay += bfhi(u4) + bfhi(u5) + bfhi(u6) + bfhi(u7);
  }
  for (; e + 1 < end; e += 2) {
    int s0 = eidx[e], s1 = eidx[e + 1];
    unsigned int u0 = h32[(size_t)s0 * 64 + lane];
    unsigned int u1 = h32[(size_t)s1 * 64 + lane];
    ax += bflo(u0) + bflo(u1);
    ay += bfhi(u0) + bfhi(u1);
  }
  if (e < end) {
    unsigned int u0 = h32[(size_t)eidx[e] * 64 + lane];
    ax += bflo(u0);
    ay += bfhi(u0);
  }
  float degp1 = (float)(end - beg + 1);
  float zx = scx * ax + degp1 * shx;
  float zy = scy * ay + degp1 * shy;
  unsigned int packed = (unsigned int)f2bf(zx) | ((unsigned int)f2bf(zy) << 16);
  ((unsigned int*)zout)[(size_t)wid * 64 + lane] = packed;
}

// ---------------- GEMM + register-resident stats/pool epilogue ----------------
// one wave = 32 rows (2 x 16-row MFMA tiles) -> 3126 waves = 12/CU (2x round-15
// TLP; acc shrinks to 64 VGPRs). kt-outer, B-frags in registers (reused 2x).
// Epilogue: bias+relu folded into acc; stats = register sums + shfl_xor;
// pool segments via ONE coalesced batch load + ballot. No barriers.

__global__ __launch_bounds__(128) void mlp_gemm_kernel(unsigned short* __restrict__ zio,
                                                       const int* __restrict__ batch,
                                                       const unsigned short* __restrict__ WtA,
                                                       const float* __restrict__ b1,
                                                       const unsigned short* __restrict__ WtB,
                                                       const float* __restrict__ b2,
                                                       float* __restrict__ statsCur,
                                                       float* __restrict__ poolU,
                                                       int poolcol, int N) {
  __shared__ unsigned short tt[2][32 * 136];
  const int tid = threadIdx.x;
  const int wv = tid >> 6;
  const int lane = tid & 63;
  const int l15 = lane & 15;
  const int eslot = lane >> 4;
  const int wid = blockIdx.x * 2 + wv;
  const int n0 = wid * 32;
  if (n0 >= N) return;  // whole-wave exit: no barriers in this kernel
  unsigned short* t = tt[wv];

  f32x4 acc[2][8];
  // ---- GEMM1: t = relu(z @ W1 + b1); A direct from global ----
#pragma unroll
  for (int rt = 0; rt < 2; ++rt)
#pragma unroll
    for (int nf = 0; nf < 8; ++nf) acc[rt][nf] = (f32x4){0.f, 0.f, 0.f, 0.f};
  for (int kt = 0; kt < 4; ++kt) {
    int kk = kt * 32 + eslot * 8;
    short8v b[8];
#pragma unroll
    for (int nf = 0; nf < 8; ++nf)
      b[nf] = *(const short8v*)&WtA[(size_t)(nf * 16 + l15) * 128 + kk];
#pragma unroll
    for (int rt = 0; rt < 2; ++rt) {
      int arow = n0 + rt * 16 + l15;
      short8v a = {0, 0, 0, 0, 0, 0, 0, 0};
      if (arow < N) a = *(const short8v*)&zio[(size_t)arow * 128 + kk];
#pragma unroll
      for (int nf = 0; nf < 8; ++nf)
        acc[rt][nf] = __builtin_amdgcn_mfma_f32_16x16x32_bf16(a, b[nf], acc[rt][nf], 0, 0, 0);
    }
  }
#pragma unroll
  for (int rt = 0; rt < 2; ++rt)
#pragma unroll
    for (int nf = 0; nf < 8; ++nf) {
      float bv = b1[nf * 16 + l15];
      int col = nf * 16 + l15;
#pragma unroll
      for (int q = 0; q < 4; ++q) {
        int row = rt * 16 + eslot * 4 + q;
        t[row * 136 + col] = f2bf(fmaxf(acc[rt][nf][q] + bv, 0.f));
      }
    }
  // wave-local LDS: program order gives write->read ordering within the wave

  // ---- GEMM2: u = relu(t @ W2 + b2) ----
#pragma unroll
  for (int rt = 0; rt < 2; ++rt)
#pragma unroll
    for (int nf = 0; nf < 8; ++nf) acc[rt][nf] = (f32x4){0.f, 0.f, 0.f, 0.f};
  for (int kt = 0; kt < 4; ++kt) {
    int kk = kt * 32 + eslot * 8;
    short8v b[8];
#pragma unroll
    for (int nf = 0; nf < 8; ++nf)
      b[nf] = *(const short8v*)&WtB[(size_t)(nf * 16 + l15) * 128 + kk];
#pragma unroll
    for (int rt = 0; rt < 2; ++rt) {
      short8v a = *(const short8v*)&t[(rt * 16 + l15) * 136 + kk];
#pragma unroll
      for (int nf = 0; nf < 8; ++nf)
        acc[rt][nf] = __builtin_amdgcn_mfma_f32_16x16x32_bf16(a, b[nf], acc[rt][nf], 0, 0, 0);
    }
  }

  // ---- epilogue: bias+relu into acc (zero invalid rows), t-write ----
#pragma unroll
  for (int rt = 0; rt < 2; ++rt)
#pragma unroll
    for (int nf = 0; nf < 8; ++nf) {
      float bv = b2[nf * 16 + l15];
      int col = nf * 16 + l15;
#pragma unroll
      for (int q = 0; q < 4; ++q) {
        int row = rt * 16 + eslot * 4 + q;
        float u = fmaxf(acc[rt][nf][q] + bv, 0.f);
        u = ((n0 + row) < N) ? u : 0.f;
        acc[rt][nf][q] = u;
        t[row * 136 + col] = f2bf(u);
      }
    }

  // store u in place (own 32 rows, coalesced 256B segments)
  for (int i = lane; i < 512; i += 64) {
    int r = i >> 4, c8 = (i & 15) << 3;
    int node = n0 + r;
    if (node < N)
      *(ushort8v*)&zio[(size_t)node * 128 + c8] = *(const ushort8v*)&t[r * 136 + c8];
  }

  // ---- BN stats: register sums + shfl_xor; lanes 0..15 push atomics ----
  float ss[8], qq[8];
#pragma unroll
  for (int nf = 0; nf < 8; ++nf) {
    float s = 0.f, qv = 0.f;
#pragma unroll
    for (int rt = 0; rt < 2; ++rt)
#pragma unroll
      for (int q = 0; q < 4; ++q) {
        float v = acc[rt][nf][q];
        s += v;
        qv += v * v;
      }
    s += __shfl_xor(s, 16); s += __shfl_xor(s, 32);
    qv += __shfl_xor(qv, 16); qv += __shfl_xor(qv, 32);
    ss[nf] = s; qq[nf] = qv;
  }
  float* myStat = statsCur + ((wid & (NSTAT - 1)) << 8);
  if (eslot == 0) {
#pragma unroll
    for (int nf = 0; nf < 8; ++nf) {
      atomicAdd(&myStat[nf * 16 + l15], ss[nf]);
      atomicAdd(&myStat[128 + nf * 16 + l15], qq[nf]);
    }
  }

  // ---- pool: ONE coalesced batch load + ballot -> segments (rows 0..31) ----
  int nvalid = min(N - n0, 32);
  int lclamp = min(lane, 31);
  int bval = batch[min(n0 + lclamp, N - 1)];
  int prevb = __shfl_up(bval, 1);
  bool isb = (lane == 0) || (lane < 32 && bval != prevb);
  unsigned long long bmask = __ballot(isb) & 0xFFFFFFFFull;
  while (bmask) {
    int ra = __ffsll((long long)bmask) - 1;
    bmask &= bmask - 1;
    if (ra >= nvalid) break;
    int rb = bmask ? (__ffsll((long long)bmask) - 1) : 32;
    rb = min(rb, nvalid);
    int g = __shfl(bval, ra);
    float ps[8];
#pragma unroll
    for (int nf = 0; nf < 8; ++nf) {
      float s = 0.f;
#pragma unroll
      for (int rt = 0; rt < 2; ++rt)
#pragma unroll
        for (int q = 0; q < 4; ++q) {
          int row = rt * 16 + eslot * 4 + q;
          s += (row >= ra && row < rb) ? acc[rt][nf][q] : 0.f;
        }
      s += __shfl_xor(s, 16); s += __shfl_xor(s, 32);
      ps[nf] = s;
    }
    if (eslot == 0) {
#pragma unroll
      for (int nf = 0; nf < 8; ++nf)
        atomicAdd(&poolU[(size_t)g * (NLAYERS * DIM) + poolcol + nf * 16 + l15], ps[nf]);
    }
  }
}

// ---------------- final h = sc2*u + sh2 (f32 out, folded sc/sh) ----------------

__global__ __launch_bounds__(256) void hwrite_kernel(const unsigned short* __restrict__ u,
                                                     const float* __restrict__ folded,
                                                     float* __restrict__ hout, int N) {
  __shared__ float scs[128], shs[128];
  if (threadIdx.x < 128) {
    scs[threadIdx.x] = folded[threadIdx.x];
    shs[threadIdx.x] = folded[128 + threadIdx.x];
  }
  __syncthreads();
  int i = blockIdx.x * 256 + threadIdx.x;  // one thread = 8 elems
  if (i >= N * 16) return;
  int row = i >> 4, c8 = (i & 15) << 3;
  ushort8v v = *(const ushort8v*)&u[(size_t)row * 128 + c8];
  float4 o0, o1;
  o0.x = scs[c8 + 0] * bf2f((unsigned short)v[0]) + shs[c8 + 0];
  o0.y = scs[c8 + 1] * bf2f((unsigned short)v[1]) + shs[c8 + 1];
  o0.z = scs[c8 + 2] * bf2f((unsigned short)v[2]) + shs[c8 + 2];
  o0.w = scs[c8 + 3] * bf2f((unsigned short)v[3]) + shs[c8 + 3];
  o1.x = scs[c8 + 4] * bf2f((unsigned short)v[4]) + shs[c8 + 4];
  o1.y = scs[c8 + 5] * bf2f((unsigned short)v[5]) + shs[c8 + 5];
  o1.z = scs[c8 + 6] * bf2f((unsigned short)v[6]) + shs[c8 + 6];
  o1.w = scs[c8 + 7] * bf2f((unsigned short)v[7]) + shs[c8 + 7];
  *(float4*)&hout[(size_t)row * 128 + c8] = o0;
  *(float4*)&hout[(size_t)row * 128 + c8 + 4] = o1;
}

// ---------------- pool finalize: pool = scL*poolU + cnt*shL (folded) ----------------

__global__ __launch_bounds__(384) void pfin_kernel(const float* __restrict__ poolU,
                                                   const float* __restrict__ folded,
                                                   const int* __restrict__ cntG,
                                                   float* __restrict__ pool) {
  int g = blockIdx.x;
  int c = threadIdx.x;  // 0..383
  int L = c >> 7, d = c & 127;
  float sc = folded[L * 256 + d];
  float sh = folded[L * 256 + 128 + d];
  pool[(size_t)g * 384 + c] = sc * poolU[(size_t)g * 384 + c] + (float)cntG[g] * sh;
}

// ---------------- launch ----------------

extern "C" void kernel_launch(void* const* d_in, const int* in_sizes, int n_in,
                              void* d_out, int out_size, void* d_ws, size_t ws_size,
                              hipStream_t stream) {
  const float* x = (const float*)d_in[0];
  const int* edge = (const int*)d_in[1];
  const int* batch = (const int*)d_in[2];
  const float* W1 = (const float*)d_in[3];
  const float* b1 = (const float*)d_in[4];
  const float* W2 = (const float*)d_in[5];
  const float* b2 = (const float*)d_in[6];
  const float* gamma = (const float*)d_in[7];
  const float* beta = (const float*)d_in[8];

  int N = in_sizes[0] / DIM;
  int E = in_sizes[1] / 2;
  const int* src = edge;
  const int* dst = edge + E;
  int NB = (N + 1023) >> 10;
  int stride = E / NB + E / (NB * 4) + 2048;

  const int statsSz = NLAYERS * NSTAT * 256;        // replicated raw stats
  char* w = (char*)d_ws;
  int* eidx = (int*)w;                w += sizeof(int) * (size_t)E;
  int* offsets = (int*)w;             w += sizeof(int) * (size_t)(N + 8);
  int* bucketCursor = (int*)w;        w += sizeof(int) * 128;
  int* bucketBase = (int*)w;          w += sizeof(int) * 128;
  float* gstats = (float*)w;          w += sizeof(float) * statsSz;
  float* folded = (float*)w;          w += sizeof(float) * NLAYERS * 256;
  float* poolU = (float*)w;           w += sizeof(float) * (size_t)NGRAPHS * NLAYERS * DIM;
  int* cntG = (int*)w;                w += sizeof(int) * 128;
  unsigned short* Wt = (unsigned short*)w;  w += sizeof(short) * 6 * 16384;
  uintptr_t a = ((uintptr_t)w + 255) & ~(uintptr_t)255;
  unsigned short* bufA = (unsigned short*)a;
  unsigned short* bufB = bufA + (size_t)N * 128;
  unsigned int* pairs = (unsigned int*)bufA;  // alias: dead before bufA first written

  float* pool = (float*)d_out;
  float* hout = (float*)d_out + (size_t)NGRAPHS * NLAYERS * DIM;

  hipMemsetAsync(bucketCursor, 0, 128 * sizeof(int), stream);
  hipMemsetAsync(gstats, 0,
                 (statsSz + NLAYERS * 256 + (size_t)NGRAPHS * NLAYERS * DIM) * sizeof(float),
                 stream);

  convw_kernel<<<6, 256, 0, stream>>>(W1, W2, Wt);
  convx_kernel<<<(N * DIM / 4 + 255) / 256, 256, 0, stream>>>(x, bufB, N * DIM / 4);

  p1_kernel<<<(E + P1CH - 1) / P1CH, 256, 0, stream>>>(src, dst, bucketCursor, pairs,
                                                       stride, E, NB);
  bscan2_kernel<<<1, 128, 0, stream>>>(bucketCursor, bucketBase, offsets, NB, N);
  p2_kernel<<<NB, 1024, 0, stream>>>(pairs, bucketCursor, bucketBase, stride, offsets,
                                     eidx, N);
  cnt_kernel<<<1, 128, 0, stream>>>(batch, cntG, N);

  float invN = 1.0f / (float)N;
  int ablk = (N + 3) / 4;
  int gblk = (N + 63) / 64;   // mlp_gemm: 2 waves x 32 rows per block
  float* st0 = gstats;
  float* st1 = gstats + NSTAT * 256;
  float* st2 = gstats + 2 * NSTAT * 256;

  // L0: x(bufB) -> z(bufA) -> u(bufA)
  agg_kernel<<<ablk, 256, 0, stream>>>(bufB, offsets, eidx, bufA, folded, 1, N);
  mlp_gemm_kernel<<<gblk, 128, 0, stream>>>(bufA, batch, Wt + 0 * 16384, b1 + 0,
                                            Wt + 3 * 16384, b2 + 0, st0, poolU, 0, N);
  bnfold_kernel<<<1, 128, 0, stream>>>(st0, gamma + 0, beta + 0, invN, folded + 0);
  // L1: u(bufA) -> z(bufB) -> u(bufB)
  agg_kernel<<<ablk, 256, 0, stream>>>(bufA, offsets, eidx, bufB, folded + 0, 0, N);
  mlp_gemm_kernel<<<gblk, 128, 0, stream>>>(bufB, batch, Wt + 1 * 16384, b1 + 128,
                                            Wt + 4 * 16384, b2 + 128, st1, poolU, 128, N);
  bnfold_kernel<<<1, 128, 0, stream>>>(st1, gamma + 128, beta + 128, invN, folded + 256);
  // L2: u(bufB) -> z(bufA) -> u(bufA)
  agg_kernel<<<ablk, 256, 0, stream>>>(bufB, offsets, eidx, bufA, folded + 256, 0, N);
  mlp_gemm_kernel<<<gblk, 128, 0, stream>>>(bufA, batch, Wt + 2 * 16384, b1 + 256,
                                            Wt + 5 * 16384, b2 + 256, st2, poolU, 256, N);
  bnfold_kernel<<<1, 128, 0, stream>>>(st2, gamma + 256, beta + 256, invN, folded + 512);

  hwrite_kernel<<<(N * 16 + 255) / 256, 256, 0, stream>>>(bufA, folded + 512, hout, N);
  pfin_kernel<<<NGRAPHS, 384, 0, stream>>>(poolU, folded, cntG, pool);
}

// Round 18
// 420.635 us; speedup vs baseline: 1.0476x; 1.0476x over previous
//
#include <hip/hip_runtime.h>

#define DIM 128
#define NLAYERS 3
#define NGRAPHS 128
#define BN_EPS 1e-5f
#define NSTAT 64   // replicated stat copies (atomic contention fix)

typedef __attribute__((ext_vector_type(8))) short short8v;
typedef __attribute__((ext_vector_type(8))) unsigned short ushort8v;
typedef __attribute__((ext_vector_type(4))) float f32x4;

__device__ __forceinline__ unsigned short f2bf(float f) {
  unsigned int x = __float_as_uint(f);
  unsigned int r = (x + 0x7fffu + ((x >> 16) & 1u)) >> 16;  // RTNE
  return (unsigned short)r;
}
__device__ __forceinline__ float bflo(unsigned int u) { return __uint_as_float(u << 16); }
__device__ __forceinline__ float bfhi(unsigned int u) { return __uint_as_float(u & 0xffff0000u); }
__device__ __forceinline__ float bf2f(unsigned short u) {
  return __uint_as_float(((unsigned int)u) << 16);
}

// ---------------- CSR build via bucketed counting sort ----------------

#define P1CH 4096

__global__ __launch_bounds__(256) void p1_kernel(const int* __restrict__ src,
                                                 const int* __restrict__ dst,
                                                 int* __restrict__ bucketCursor,
                                                 unsigned int* __restrict__ pairs,
                                                 int stride, int E, int NB) {
  __shared__ int cnt[128];
  __shared__ int base[128];
  int t = threadIdx.x;
  int e0 = blockIdx.x * P1CH;
  int e1 = min(e0 + P1CH, E);
  if (t < NB) cnt[t] = 0;
  __syncthreads();
  for (int e = e0 + t; e < e1; e += 256) atomicAdd(&cnt[dst[e] >> 10], 1);
  __syncthreads();
  if (t < NB) {
    base[t] = atomicAdd(&bucketCursor[t], cnt[t]);
    cnt[t] = 0;
  }
  __syncthreads();
  for (int e = e0 + t; e < e1; e += 256) {
    int d = dst[e];
    int b = d >> 10;
    int p = atomicAdd(&cnt[b], 1) + base[b];
    pairs[(size_t)b * stride + p] = ((unsigned int)(d & 1023) << 20) | (unsigned int)src[e];
  }
}

// block 0: scan bucket sizes -> bases + offsets[N]; block 1: per-graph counts
__global__ __launch_bounds__(128) void bscan2cnt_kernel(const int* __restrict__ bucketCursor,
                                                        int* __restrict__ bucketBase,
                                                        int* __restrict__ offsets,
                                                        const int* __restrict__ batch,
                                                        int* __restrict__ cntG,
                                                        int NB, int N) {
  int t = threadIdx.x;
  if (blockIdx.x == 1) {
    int g = t;
    int lo = 0, hi = N;
    while (lo < hi) { int mid = (lo + hi) >> 1; if (batch[mid] < g) lo = mid + 1; else hi = mid; }
    int a = lo;
    lo = 0; hi = N;
    while (lo < hi) { int mid = (lo + hi) >> 1; if (batch[mid] < g + 1) lo = mid + 1; else hi = mid; }
    cntG[g] = lo - a;
    return;
  }
  __shared__ int p[128];
  p[t] = (t < NB) ? bucketCursor[t] : 0;
  __syncthreads();
  for (int off = 1; off < 128; off <<= 1) {
    int v = (t >= off) ? p[t - off] : 0;
    __syncthreads();
    p[t] += v;
    __syncthreads();
  }
  if (t < NB) bucketBase[t] = (t == 0) ? 0 : p[t - 1];
  if (t == 0) offsets[N] = p[127];
}

__global__ __launch_bounds__(1024) void p2_kernel(const unsigned int* __restrict__ pairs,
                                                  const int* __restrict__ bucketCursor,
                                                  const int* __restrict__ bucketBase,
                                                  int stride, int* __restrict__ offsets,
                                                  int* __restrict__ eidx, int N) {
  __shared__ int cur[1024];
  int b = blockIdx.x;
  int t = threadIdx.x;
  int sz = bucketCursor[b];
  int ebase = bucketBase[b];
  const unsigned int* pp = pairs + (size_t)b * stride;
  cur[t] = 0;
  __syncthreads();
  for (int i = t; i < sz; i += 1024) atomicAdd(&cur[pp[i] >> 20], 1);
  __syncthreads();
  int v = cur[t];
  __syncthreads();
  cur[t] = v;
  __syncthreads();
  for (int off = 1; off < 1024; off <<= 1) {
    int u = (t >= off) ? cur[t - off] : 0;
    __syncthreads();
    cur[t] += u;
    __syncthreads();
  }
  int excl = cur[t] - v;
  int node = b * 1024 + t;
  if (node < N) offsets[node] = ebase + excl;
  cur[t] = excl;
  __syncthreads();
  for (int i = t; i < sz; i += 1024) {
    unsigned int pv = pp[i];
    int p = atomicAdd(&cur[pv >> 20], 1);
    eidx[ebase + p] = (int)(pv & 0xFFFFFu);
  }
}

// ---------------- merged conversions: blocks 0..5 = weights, rest = x ----------------

__global__ __launch_bounds__(256) void conv_kernel(const float* __restrict__ W1,
                                                   const float* __restrict__ W2,
                                                   const float* __restrict__ x,
                                                   unsigned short* __restrict__ Wt,
                                                   unsigned short* __restrict__ xout,
                                                   int nquads) {
  if (blockIdx.x < 6) {
    int m = blockIdx.x;
    const float* W = (m < 3) ? (W1 + (size_t)m * 16384) : (W2 + (size_t)(m - 3) * 16384);
    unsigned short* out = Wt + (size_t)m * 16384;
    __shared__ unsigned short t[128 * 130];
    for (int i = threadIdx.x; i < 16384; i += 256) {
      int k = i >> 7, n = i & 127;
      t[n * 130 + k] = f2bf(W[i]);
    }
    __syncthreads();
    for (int i = threadIdx.x; i < 16384; i += 256) {
      int n = i >> 7, k = i & 127;
      out[i] = t[n * 130 + k];
    }
    return;
  }
  int i = (blockIdx.x - 6) * 256 + threadIdx.x;
  if (i < nquads) {
    float4 v = ((const float4*)x)[i];
    ushort4 o;
    o.x = f2bf(v.x); o.y = f2bf(v.y); o.z = f2bf(v.z); o.w = f2bf(v.w);
    ((ushort4*)xout)[i] = o;
  }
}

// ---------------- BN fold: sum NSTAT replicas -> sc[128], sh[128] ----------------

__global__ __launch_bounds__(128) void bnfold_kernel(const float* __restrict__ statsRaw,
                                                     const float* __restrict__ gammaL,
                                                     const float* __restrict__ betaL,
                                                     float invN, float* __restrict__ folded) {
  int d = threadIdx.x;
  float s = 0.f, q = 0.f;
#pragma unroll
  for (int k = 0; k < NSTAT; ++k) {
    s += statsRaw[k * 256 + d];
    q += statsRaw[k * 256 + 128 + d];
  }
  float mu = s * invN;
  float var = q * invN - mu * mu;
  float sc = gammaL[d] * rsqrtf(var + BN_EPS);
  folded[d] = sc;
  folded[128 + d] = betaL[d] - mu * sc;
}

// ---------------- aggregation with fused prev-layer BN (folded sc/sh) ----------------
// one wave per node; lane owns dims {2l, 2l+1}; 8 row-loads (2KB) in flight

__global__ __launch_bounds__(256) void agg_kernel(const unsigned short* __restrict__ uin,
                                                  const int* __restrict__ offsets,
                                                  const int* __restrict__ eidx,
                                                  unsigned short* __restrict__ zout,
                                                  const float* __restrict__ foldedPrev,
                                                  int isFirst, int N) {
  int wid = (blockIdx.x * 256 + threadIdx.x) >> 6;
  int lane = threadIdx.x & 63;
  if (wid >= N) return;
  float scx = 1.f, scy = 1.f, shx = 0.f, shy = 0.f;
  if (!isFirst) {
    int d0 = lane * 2;
    float2 scv = *(const float2*)&foldedPrev[d0];
    float2 shv = *(const float2*)&foldedPrev[128 + d0];
    scx = scv.x; scy = scv.y; shx = shv.x; shy = shv.y;
  }
  const unsigned int* h32 = (const unsigned int*)uin;
  unsigned int own = h32[(size_t)wid * 64 + lane];
  float ax = bflo(own), ay = bfhi(own);
  int beg = offsets[wid], end = offsets[wid + 1];
  int e = beg;
  for (; e + 7 < end; e += 8) {
    int s0 = eidx[e], s1 = eidx[e + 1], s2 = eidx[e + 2], s3 = eidx[e + 3];
    int s4 = eidx[e + 4], s5 = eidx[e + 5], s6 = eidx[e + 6], s7 = eidx[e + 7];
    unsigned int u0 = h32[(size_t)s0 * 64 + lane];
    unsigned int u1 = h32[(size_t)s1 * 64 + lane];
    unsigned int u2 = h32[(size_t)s2 * 64 + lane];
    unsigned int u3 = h32[(size_t)s3 * 64 + lane];
    unsigned int u4 = h32[(size_t)s4 * 64 + lane];
    unsigned int u5 = h32[(size_t)s5 * 64 + lane];
    unsigned int u6 = h32[(size_t)s6 * 64 + lane];
    unsigned int u7 = h32[(size_t)s7 * 64 + lane];
    ax += bflo(u0) + bflo(u1) + bflo(u2) + bflo(u3);
    ay += bfhi(u0) + bfhi(u1) + bfhi(u2) + bfhi(u3);
    ax += bflo(u4) + bflo(u5) + bflo(u6) + bflo(u7);
    ay += bfhi(u4) + bfhi(u5) + bfhi(u6) + bfhi(u7);
  }
  for (; e + 1 < end; e += 2) {
    int s0 = eidx[e], s1 = eidx[e + 1];
    unsigned int u0 = h32[(size_t)s0 * 64 + lane];
    unsigned int u1 = h32[(size_t)s1 * 64 + lane];
    ax += bflo(u0) + bflo(u1);
    ay += bfhi(u0) + bfhi(u1);
  }
  if (e < end) {
    unsigned int u0 = h32[(size_t)eidx[e] * 64 + lane];
    ax += bflo(u0);
    ay += bfhi(u0);
  }
  float degp1 = (float)(end - beg + 1);
  float zx = scx * ax + degp1 * shx;
  float zy = scy * ay + degp1 * shy;
  unsigned int packed = (unsigned int)f2bf(zx) | ((unsigned int)f2bf(zy) << 16);
  ((unsigned int*)zout)[(size_t)wid * 64 + lane] = packed;
}

// ---------------- GEMM + register-resident stats/pool epilogue ----------------
// one wave = 64 rows (4 x 16-row MFMA tiles), kt-outer, B-frags in registers.
// Epilogue: bias+relu folded into acc; stats = register sums + shfl_xor;
// pool segments found via ONE coalesced batch load + ballot. No barriers.

__global__ __launch_bounds__(128) void mlp_gemm_kernel(unsigned short* __restrict__ zio,
                                                       const int* __restrict__ batch,
                                                       const unsigned short* __restrict__ WtA,
                                                       const float* __restrict__ b1,
                                                       const unsigned short* __restrict__ WtB,
                                                       const float* __restrict__ b2,
                                                       float* __restrict__ statsCur,
                                                       float* __restrict__ poolU,
                                                       int poolcol, int N) {
  __shared__ unsigned short tt[2][64 * 136];
  const int tid = threadIdx.x;
  const int wv = tid >> 6;
  const int lane = tid & 63;
  const int l15 = lane & 15;
  const int eslot = lane >> 4;
  const int wid = blockIdx.x * 2 + wv;
  const int n0 = wid * 64;
  if (n0 >= N) return;  // whole-wave exit: no barriers in this kernel
  unsigned short* t = tt[wv];

  f32x4 acc[4][8];
  // ---- GEMM1: t = relu(z @ W1 + b1); A direct from global ----
#pragma unroll
  for (int rt = 0; rt < 4; ++rt)
#pragma unroll
    for (int nf = 0; nf < 8; ++nf) acc[rt][nf] = (f32x4){0.f, 0.f, 0.f, 0.f};
  for (int kt = 0; kt < 4; ++kt) {
    int kk = kt * 32 + eslot * 8;
    short8v b[8];
#pragma unroll
    for (int nf = 0; nf < 8; ++nf)
      b[nf] = *(const short8v*)&WtA[(size_t)(nf * 16 + l15) * 128 + kk];
#pragma unroll
    for (int rt = 0; rt < 4; ++rt) {
      int arow = n0 + rt * 16 + l15;
      short8v a = {0, 0, 0, 0, 0, 0, 0, 0};
      if (arow < N) a = *(const short8v*)&zio[(size_t)arow * 128 + kk];
#pragma unroll
      for (int nf = 0; nf < 8; ++nf)
        acc[rt][nf] = __builtin_amdgcn_mfma_f32_16x16x32_bf16(a, b[nf], acc[rt][nf], 0, 0, 0);
    }
  }
#pragma unroll
  for (int rt = 0; rt < 4; ++rt)
#pragma unroll
    for (int nf = 0; nf < 8; ++nf) {
      float bv = b1[nf * 16 + l15];
      int col = nf * 16 + l15;
#pragma unroll
      for (int q = 0; q < 4; ++q) {
        int row = rt * 16 + eslot * 4 + q;
        t[row * 136 + col] = f2bf(fmaxf(acc[rt][nf][q] + bv, 0.f));
      }
    }
  // wave-local LDS: program order gives write->read ordering within the wave

  // ---- GEMM2: u = relu(t @ W2 + b2) ----
#pragma unroll
  for (int rt = 0; rt < 4; ++rt)
#pragma unroll
    for (int nf = 0; nf < 8; ++nf) acc[rt][nf] = (f32x4){0.f, 0.f, 0.f, 0.f};
  for (int kt = 0; kt < 4; ++kt) {
    int kk = kt * 32 + eslot * 8;
    short8v b[8];
#pragma unroll
    for (int nf = 0; nf < 8; ++nf)
      b[nf] = *(const short8v*)&WtB[(size_t)(nf * 16 + l15) * 128 + kk];
#pragma unroll
    for (int rt = 0; rt < 4; ++rt) {
      short8v a = *(const short8v*)&t[(rt * 16 + l15) * 136 + kk];
#pragma unroll
      for (int nf = 0; nf < 8; ++nf)
        acc[rt][nf] = __builtin_amdgcn_mfma_f32_16x16x32_bf16(a, b[nf], acc[rt][nf], 0, 0, 0);
    }
  }

  // ---- epilogue: bias+relu into acc (zero invalid rows), t-write ----
#pragma unroll
  for (int rt = 0; rt < 4; ++rt)
#pragma unroll
    for (int nf = 0; nf < 8; ++nf) {
      float bv = b2[nf * 16 + l15];
      int col = nf * 16 + l15;
#pragma unroll
      for (int q = 0; q < 4; ++q) {
        int row = rt * 16 + eslot * 4 + q;
        float u = fmaxf(acc[rt][nf][q] + bv, 0.f);
        u = ((n0 + row) < N) ? u : 0.f;
        acc[rt][nf][q] = u;
        t[row * 136 + col] = f2bf(u);
      }
    }

  // store u in place (own 64 rows, coalesced 256B segments)
  for (int i = lane; i < 1024; i += 64) {
    int r = i >> 4, c8 = (i & 15) << 3;
    int node = n0 + r;
    if (node < N)
      *(ushort8v*)&zio[(size_t)node * 128 + c8] = *(const ushort8v*)&t[r * 136 + c8];
  }

  // ---- BN stats: register sums + shfl_xor; lanes 0..15 push atomics ----
  float ss[8], qq[8];
#pragma unroll
  for (int nf = 0; nf < 8; ++nf) {
    float s = 0.f, qv = 0.f;
#pragma unroll
    for (int rt = 0; rt < 4; ++rt)
#pragma unroll
      for (int q = 0; q < 4; ++q) {
        float v = acc[rt][nf][q];
        s += v;
        qv += v * v;
      }
    s += __shfl_xor(s, 16); s += __shfl_xor(s, 32);
    qv += __shfl_xor(qv, 16); qv += __shfl_xor(qv, 32);
    ss[nf] = s; qq[nf] = qv;
  }
  float* myStat = statsCur + ((wid & (NSTAT - 1)) << 8);
  if (eslot == 0) {
#pragma unroll
    for (int nf = 0; nf < 8; ++nf) {
      atomicAdd(&myStat[nf * 16 + l15], ss[nf]);
      atomicAdd(&myStat[128 + nf * 16 + l15], qq[nf]);
    }
  }

  // ---- pool: ONE coalesced batch load + ballot -> segments; masked reg sums ----
  int nvalid = min(N - n0, 64);
  int bval = batch[min(n0 + lane, N - 1)];
  int prevb = __shfl_up(bval, 1);
  bool isb = (lane == 0) || (bval != prevb);
  unsigned long long bmask = __ballot(isb);
  while (bmask) {
    int ra = __ffsll((long long)bmask) - 1;
    bmask &= bmask - 1;
    if (ra >= nvalid) break;
    int rb = bmask ? (__ffsll((long long)bmask) - 1) : 64;
    rb = min(rb, nvalid);
    int g = __shfl(bval, ra);
    float ps[8];
#pragma unroll
    for (int nf = 0; nf < 8; ++nf) {
      float s = 0.f;
#pragma unroll
      for (int rt = 0; rt < 4; ++rt)
#pragma unroll
        for (int q = 0; q < 4; ++q) {
          int row = rt * 16 + eslot * 4 + q;
          s += (row >= ra && row < rb) ? acc[rt][nf][q] : 0.f;
        }
      s += __shfl_xor(s, 16); s += __shfl_xor(s, 32);
      ps[nf] = s;
    }
    if (eslot == 0) {
#pragma unroll
      for (int nf = 0; nf < 8; ++nf)
        atomicAdd(&poolU[(size_t)g * (NLAYERS * DIM) + poolcol + nf * 16 + l15], ps[nf]);
    }
  }
}

// ---------------- final h = sc2*u + sh2 (f32 out, folded sc/sh) ----------------

__global__ __launch_bounds__(256) void hwrite_kernel(const unsigned short* __restrict__ u,
                                                     const float* __restrict__ folded,
                                                     float* __restrict__ hout, int N) {
  __shared__ float scs[128], shs[128];
  if (threadIdx.x < 128) {
    scs[threadIdx.x] = folded[threadIdx.x];
    shs[threadIdx.x] = folded[128 + threadIdx.x];
  }
  __syncthreads();
  int i = blockIdx.x * 256 + threadIdx.x;  // one thread = 8 elems
  if (i >= N * 16) return;
  int row = i >> 4, c8 = (i & 15) << 3;
  ushort8v v = *(const ushort8v*)&u[(size_t)row * 128 + c8];
  float4 o0, o1;
  o0.x = scs[c8 + 0] * bf2f((unsigned short)v[0]) + shs[c8 + 0];
  o0.y = scs[c8 + 1] * bf2f((unsigned short)v[1]) + shs[c8 + 1];
  o0.z = scs[c8 + 2] * bf2f((unsigned short)v[2]) + shs[c8 + 2];
  o0.w = scs[c8 + 3] * bf2f((unsigned short)v[3]) + shs[c8 + 3];
  o1.x = scs[c8 + 4] * bf2f((unsigned short)v[4]) + shs[c8 + 4];
  o1.y = scs[c8 + 5] * bf2f((unsigned short)v[5]) + shs[c8 + 5];
  o1.z = scs[c8 + 6] * bf2f((unsigned short)v[6]) + shs[c8 + 6];
  o1.w = scs[c8 + 7] * bf2f((unsigned short)v[7]) + shs[c8 + 7];
  *(float4*)&hout[(size_t)row * 128 + c8] = o0;
  *(float4*)&hout[(size_t)row * 128 + c8 + 4] = o1;
}

// ---------------- pool finalize: pool = scL*poolU + cnt*shL (folded) ----------------

__global__ __launch_bounds__(384) void pfin_kernel(const float* __restrict__ poolU,
                                                   const float* __restrict__ folded,
                                                   const int* __restrict__ cntG,
                                                   float* __restrict__ pool) {
  int g = blockIdx.x;
  int c = threadIdx.x;  // 0..383
  int L = c >> 7, d = c & 127;
  float sc = folded[L * 256 + d];
  float sh = folded[L * 256 + 128 + d];
  pool[(size_t)g * 384 + c] = sc * poolU[(size_t)g * 384 + c] + (float)cntG[g] * sh;
}

// ---------------- launch ----------------

extern "C" void kernel_launch(void* const* d_in, const int* in_sizes, int n_in,
                              void* d_out, int out_size, void* d_ws, size_t ws_size,
                              hipStream_t stream) {
  const float* x = (const float*)d_in[0];
  const int* edge = (const int*)d_in[1];
  const int* batch = (const int*)d_in[2];
  const float* W1 = (const float*)d_in[3];
  const float* b1 = (const float*)d_in[4];
  const float* W2 = (const float*)d_in[5];
  const float* b2 = (const float*)d_in[6];
  const float* gamma = (const float*)d_in[7];
  const float* beta = (const float*)d_in[8];

  int N = in_sizes[0] / DIM;
  int E = in_sizes[1] / 2;
  const int* src = edge;
  const int* dst = edge + E;
  int NB = (N + 1023) >> 10;
  int stride = E / NB + E / (NB * 4) + 2048;

  const int statsSz = NLAYERS * NSTAT * 256;        // replicated raw stats
  char* w = (char*)d_ws;
  int* eidx = (int*)w;                w += sizeof(int) * (size_t)E;
  int* offsets = (int*)w;             w += sizeof(int) * (size_t)(N + 8);
  int* bucketBase = (int*)w;          w += sizeof(int) * 128;
  int* bucketCursor = (int*)w;        w += sizeof(int) * 128;   // adjacent to zero-region
  float* gstats = (float*)w;          w += sizeof(float) * statsSz;
  float* folded = (float*)w;          w += sizeof(float) * NLAYERS * 256;
  float* poolU = (float*)w;           w += sizeof(float) * (size_t)NGRAPHS * NLAYERS * DIM;
  int* cntG = (int*)w;                w += sizeof(int) * 128;
  unsigned short* Wt = (unsigned short*)w;  w += sizeof(short) * 6 * 16384;
  uintptr_t a = ((uintptr_t)w + 255) & ~(uintptr_t)255;
  unsigned short* bufA = (unsigned short*)a;
  unsigned short* bufB = bufA + (size_t)N * 128;
  unsigned int* pairs = (unsigned int*)bufA;  // alias: dead before bufA first written

  float* pool = (float*)d_out;
  float* hout = (float*)d_out + (size_t)NGRAPHS * NLAYERS * DIM;

  // single memset covers bucketCursor + gstats + folded + poolU (contiguous)
  hipMemsetAsync(bucketCursor, 0,
                 128 * sizeof(int) +
                 (statsSz + NLAYERS * 256 + (size_t)NGRAPHS * NLAYERS * DIM) * sizeof(float),
                 stream);

  int nquads = N * DIM / 4;
  conv_kernel<<<6 + (nquads + 255) / 256, 256, 0, stream>>>(W1, W2, x, Wt, bufB, nquads);

  p1_kernel<<<(E + P1CH - 1) / P1CH, 256, 0, stream>>>(src, dst, bucketCursor, pairs,
                                                       stride, E, NB);
  bscan2cnt_kernel<<<2, 128, 0, stream>>>(bucketCursor, bucketBase, offsets, batch, cntG,
                                          NB, N);
  p2_kernel<<<NB, 1024, 0, stream>>>(pairs, bucketCursor, bucketBase, stride, offsets,
                                     eidx, N);

  float invN = 1.0f / (float)N;
  int ablk = (N + 3) / 4;
  int gblk = (N + 127) / 128;   // mlp_gemm: 2 waves x 64 rows per block
  float* st0 = gstats;
  float* st1 = gstats + NSTAT * 256;
  float* st2 = gstats + 2 * NSTAT * 256;

  // L0: x(bufB) -> z(bufA) -> u(bufA)
  agg_kernel<<<ablk, 256, 0, stream>>>(bufB, offsets, eidx, bufA, folded, 1, N);
  mlp_gemm_kernel<<<gblk, 128, 0, stream>>>(bufA, batch, Wt + 0 * 16384, b1 + 0,
                                            Wt + 3 * 16384, b2 + 0, st0, poolU, 0, N);
  bnfold_kernel<<<1, 128, 0, stream>>>(st0, gamma + 0, beta + 0, invN, folded + 0);
  // L1: u(bufA) -> z(bufB) -> u(bufB)
  agg_kernel<<<ablk, 256, 0, stream>>>(bufA, offsets, eidx, bufB, folded + 0, 0, N);
  mlp_gemm_kernel<<<gblk, 128, 0, stream>>>(bufB, batch, Wt + 1 * 16384, b1 + 128,
                                            Wt + 4 * 16384, b2 + 128, st1, poolU, 128, N);
  bnfold_kernel<<<1, 128, 0, stream>>>(st1, gamma + 128, beta + 128, invN, folded + 256);
  // L2: u(bufB) -> z(bufA) -> u(bufA)
  agg_kernel<<<ablk, 256, 0, stream>>>(bufB, offsets, eidx, bufA, folded + 256, 0, N);
  mlp_gemm_kernel<<<gblk, 128, 0, stream>>>(bufA, batch, Wt + 2 * 16384, b1 + 256,
                                            Wt + 5 * 16384, b2 + 256, st2, poolU, 256, N);
  bnfold_kernel<<<1, 128, 0, stream>>>(st2, gamma + 256, beta + 256, invN, folded + 512);

  hwrite_kernel<<<(N * 16 + 255) / 256, 256, 0, stream>>>(bufA, folded + 512, hout, N);
  pfin_kernel<<<NGRAPHS, 384, 0, stream>>>(poolU, folded, cntG, pool);
}